// Round 14
// baseline (335.282 us; speedup 1.0000x reference)
//
#include <hip/hip_runtime.h>

// ---------------------------------------------------------------------------
// GATv2 (2 layers) + mean-pool + MLP for MI355X.
// N=50000 nodes, E=800000 edges (+N self loops), IN=128, HID=64, HEADS=2,
// OUT=3, 64 graphs. Output: [64,3] float32.
// R1: k_agg2 pool atomic storm fixed (LDS pre-reduction). 1128 -> 803 us.
// R2: CSR + per-node online softmax; edge phases fused.   803 -> 515 us.
// R3: fused1 2-edge ILP + reg src cache + W2-proj fused.   515 -> 394 us.
// R4: fused1 2 nodes/wave + 4-edge ILP + batched softmax.  394 -> 368 us.
// R5: gemm 128x128 reg-blocked (LDS 72KB->16KB).            368 -> 343 us.
// R6: DPP rotate-reduce + exp2 domain; gemm 64x128/4x8.     343 -> 337 us.
// R7: 8-edge unroll flat. R8-R10: degree-sort detour regressed; reverted.
// R11: 3-phase parallel scan (single-block scan was 100us!). 422 -> 329 us.
// R12: xl1 message table bf16 (gather 512->256B/edge).       329 -> 326 us.
// R13: k_fill atomic-free (rank from k_deg); gemm merged.    326 -> 286 us.
// R14: gemm was LDS-throughput-bound (1.25 B/FMA -> 38us LDS floor vs 21us
//     FMA floor; VALUBusy 39%). Now 8x16 micro-tile (0.75 B/FMA), 128-thr
//     blocks, W tile strided x20 floats (aligned, 2-way banks only).
//     Bit-identical math, same grid (782).
// ---------------------------------------------------------------------------

#define NGRAPH 64
#define LOG2E 1.4426950408889634f

// v_mov_dpp row_ror:k (16-lane rows). Valid reduce permutation for
// commutative ops; leaves every lane of the row with the full result.
#define DPP_ROR(C, x) \
  __int_as_float(__builtin_amdgcn_update_dpp(0, __float_as_int(x), (0x120 | C), 0xF, 0xF, false))

__device__ __forceinline__ float rowsum16(float v) {
  v += DPP_ROR(8, v);
  v += DPP_ROR(4, v);
  v += DPP_ROR(2, v);
  v += DPP_ROR(1, v);
  return v;
}

__device__ __forceinline__ unsigned bf16rne(float f) {
  unsigned u = __float_as_uint(f);
  return (u + 0x7FFFu + ((u >> 16) & 1u)) >> 16;
}

// ---------------------------------------------------------------------------
// The atomic's return value IS this edge's rank among its dst's edges.
__global__ void k_deg(const int* __restrict__ ei, int E, int Et,
                      int* __restrict__ deg, int* __restrict__ rank) {
  int e = blockIdx.x * blockDim.x + threadIdx.x;
  if (e >= Et) return;
  int d = (e < E) ? ei[E + e] : (e - E);  // dst only
  rank[e] = atomicAdd(&deg[d], 1);        // coalesced store of the rank
}

// ---------------------------------------------------------------------------
// 3-phase parallel exclusive scan of deg[0..n) -> row_ptr[0..n].
__global__ __launch_bounds__(256) void k_scan_part(const int* __restrict__ deg,
                                                   int* __restrict__ bsum, int n) {
  __shared__ int sd[256];
  int t = threadIdx.x;
  int i = blockIdx.x * 1024 + t * 4;
  int s = 0;
  if (i + 4 <= n) {
    int4 d = *(const int4*)&deg[i];
    s = d.x + d.y + d.z + d.w;
  } else {
    for (int j = i; j < min(i + 4, n); ++j) s += deg[j];
  }
  sd[t] = s;
  __syncthreads();
  for (int off = 128; off; off >>= 1) {
    if (t < off) sd[t] += sd[t + off];
    __syncthreads();
  }
  if (t == 0) bsum[blockIdx.x] = sd[0];
}

__global__ __launch_bounds__(64) void k_scan_top(int* __restrict__ bsum, int nb) {
  __shared__ int s[64];
  int t = threadIdx.x;
  s[t] = (t < nb) ? bsum[t] : 0;
  __syncthreads();
  int acc = 0;
  for (int j = 0; j < t; ++j) acc += s[j];
  if (t < nb) bsum[t] = acc;
}

__global__ __launch_bounds__(256) void k_scan_write(const int* __restrict__ deg,
                                                    const int* __restrict__ bsum,
                                                    int* __restrict__ row_ptr, int n) {
  __shared__ int sd[256];
  int t = threadIdx.x;
  int i = blockIdx.x * 1024 + t * 4;
  int4 d = make_int4(0, 0, 0, 0);
  bool full = (i + 4 <= n);
  if (full) d = *(const int4*)&deg[i];
  else {
    if (i + 0 < n) d.x = deg[i + 0];
    if (i + 1 < n) d.y = deg[i + 1];
    if (i + 2 < n) d.z = deg[i + 2];
    if (i + 3 < n) d.w = deg[i + 3];
  }
  int s = d.x + d.y + d.z + d.w;
  sd[t] = s;
  __syncthreads();
  for (int off = 1; off < 256; off <<= 1) {  // Hillis-Steele inclusive
    int v = (t >= off) ? sd[t - off] : 0;
    __syncthreads();
    sd[t] += v;
    __syncthreads();
  }
  int ex = sd[t] - s + bsum[blockIdx.x];
  int4 r;
  r.x = ex;
  r.y = ex + d.x;
  r.z = r.y + d.y;
  r.w = r.z + d.z;
  if (full) {
    *(int4*)&row_ptr[i] = r;
    if (i + 4 == n) row_ptr[n] = r.w + d.w;
  } else if (i < n) {
    int run = ex;
    int vals[4] = {d.x, d.y, d.z, d.w};
    for (int j = 0; j < 4 && i + j < n; ++j) {
      row_ptr[i + j] = run;
      run += vals[j];
    }
    if (i <= n && i + 4 > n) row_ptr[n] = run;
  }
}

// no atomic — slot is row_ptr[d] + precomputed rank.
__global__ void k_fill(const int* __restrict__ ei, int E, int Et,
                       const int* __restrict__ row_ptr,
                       const int* __restrict__ rank,
                       int* __restrict__ csr_src) {
  int e = blockIdx.x * blockDim.x + threadIdx.x;
  if (e >= Et) return;
  int s, d;
  if (e < E) { s = ei[e]; d = ei[E + e]; }
  else       { s = e - E; d = s; }
  csr_src[row_ptr[d] + rank[e]] = s;
}

// ---------------------------------------------------------------------------
// R14: one dispatch computes xl1 = x@W1l (BF16 out) AND xr1 = x@W1r (fp32).
// Block: 64 rows x 256 combined cols, 128 threads, 8x16 micro-tile.
// Per k: 2 a-b128 + 4 b-b128 = 96 B LDS per 128 FMA (0.75 B/FMA).
// W tile cols stored at stride 20 floats (16B-aligned, <=2-way banks).
// FMA order per output identical to the 2-pass version (bit-identical).
__global__ __launch_bounds__(128) void k_gemm128(const float* __restrict__ x,
                                                 const float* __restrict__ Wl,
                                                 const float* __restrict__ Wr,
                                                 unsigned short* __restrict__ outl,
                                                 float* __restrict__ outr, int n) {
  __shared__ __align__(16) float xs[16][72];    // x tile transposed [k][row]
  __shared__ __align__(16) float wsc[16][320];  // combined W: [k][cg*20 + j]
  int t = threadIdx.x;
  int rg = t >> 4;   // 0..7  -> rows rg*8..rg*8+7
  int cg = t & 15;   // 0..15 -> combined cols cg*16..cg*16+15
  int r0 = blockIdx.x * 64;
  float acc[8][16] = {};

  for (int k0 = 0; k0 < 128; k0 += 16) {
    float4 xv[2];
#pragma unroll
    for (int p = 0; p < 2; ++p) {
      int idx = t + 128 * p;
      int sr = idx & 63, skq = idx >> 6;
      int gr = r0 + sr;
      xv[p] = make_float4(0.f, 0.f, 0.f, 0.f);
      if (gr < n) xv[p] = *(const float4*)&x[(size_t)gr * 128 + k0 + skq * 4];
    }
    float4 wv[8];
#pragma unroll
    for (int p = 0; p < 8; ++p) {
      int idx = t + 128 * p;
      int k = idx >> 6, cq = idx & 63;
      const float* src = (cq < 32) ? &Wl[(size_t)(k0 + k) * 128 + cq * 4]
                                   : &Wr[(size_t)(k0 + k) * 128 + (cq - 32) * 4];
      wv[p] = *(const float4*)src;
    }
    __syncthreads();
#pragma unroll
    for (int p = 0; p < 2; ++p) {
      int idx = t + 128 * p;
      int sr = idx & 63, skq = idx >> 6;
      xs[skq * 4 + 0][sr] = xv[p].x;
      xs[skq * 4 + 1][sr] = xv[p].y;
      xs[skq * 4 + 2][sr] = xv[p].z;
      xs[skq * 4 + 3][sr] = xv[p].w;
    }
#pragma unroll
    for (int p = 0; p < 8; ++p) {
      int idx = t + 128 * p;
      int k = idx >> 6, cq = idx & 63;
      *(float4*)&wsc[k][(cq >> 2) * 20 + (cq & 3) * 4] = wv[p];
    }
    __syncthreads();
#pragma unroll
    for (int k = 0; k < 16; ++k) {
      float4 a0 = *(const float4*)&xs[k][rg * 8];
      float4 a1 = *(const float4*)&xs[k][rg * 8 + 4];
      float4 b0 = *(const float4*)&wsc[k][cg * 20 + 0];
      float4 b1 = *(const float4*)&wsc[k][cg * 20 + 4];
      float4 b2 = *(const float4*)&wsc[k][cg * 20 + 8];
      float4 b3 = *(const float4*)&wsc[k][cg * 20 + 12];
      float a[8] = {a0.x, a0.y, a0.z, a0.w, a1.x, a1.y, a1.z, a1.w};
      float b[16] = {b0.x, b0.y, b0.z, b0.w, b1.x, b1.y, b1.z, b1.w,
                     b2.x, b2.y, b2.z, b2.w, b3.x, b3.y, b3.z, b3.w};
#pragma unroll
      for (int i = 0; i < 8; ++i)
#pragma unroll
        for (int j = 0; j < 16; ++j)
          acc[i][j] = fmaf(a[i], b[j], acc[i][j]);
    }
  }
  if (cg < 8) {  // bf16 xl1 columns cg*16..+15
#pragma unroll
    for (int i = 0; i < 8; ++i) {
      int gr = r0 + rg * 8 + i;
      if (gr < n) {
        uint4 q0, q1;
        q0.x = bf16rne(acc[i][0]) | (bf16rne(acc[i][1]) << 16);
        q0.y = bf16rne(acc[i][2]) | (bf16rne(acc[i][3]) << 16);
        q0.z = bf16rne(acc[i][4]) | (bf16rne(acc[i][5]) << 16);
        q0.w = bf16rne(acc[i][6]) | (bf16rne(acc[i][7]) << 16);
        q1.x = bf16rne(acc[i][8]) | (bf16rne(acc[i][9]) << 16);
        q1.y = bf16rne(acc[i][10]) | (bf16rne(acc[i][11]) << 16);
        q1.z = bf16rne(acc[i][12]) | (bf16rne(acc[i][13]) << 16);
        q1.w = bf16rne(acc[i][14]) | (bf16rne(acc[i][15]) << 16);
        *(uint4*)&outl[(size_t)gr * 128 + cg * 16] = q0;
        *(uint4*)&outl[(size_t)gr * 128 + cg * 16 + 8] = q1;
      }
    }
  } else {  // fp32 xr1 columns (cg-8)*16..+15
    int c0 = (cg - 8) * 16;
#pragma unroll
    for (int i = 0; i < 8; ++i) {
      int gr = r0 + rg * 8 + i;
      if (gr < n) {
        *(float4*)&outr[(size_t)gr * 128 + c0 + 0] =
            make_float4(acc[i][0], acc[i][1], acc[i][2], acc[i][3]);
        *(float4*)&outr[(size_t)gr * 128 + c0 + 4] =
            make_float4(acc[i][4], acc[i][5], acc[i][6], acc[i][7]);
        *(float4*)&outr[(size_t)gr * 128 + c0 + 8] =
            make_float4(acc[i][8], acc[i][9], acc[i][10], acc[i][11]);
        *(float4*)&outr[(size_t)gr * 128 + c0 + 12] =
            make_float4(acc[i][12], acc[i][13], acc[i][14], acc[i][15]);
      }
    }
  }
}

// ---------------------------------------------------------------------------
// fused layer-1 edge phase + layer-2 input projection.
// TWO nodes per wave: lanes 0-31 = node 2w, 32-63 = node 2w+1. Lane holds 4
// channels; 16-lane head groups = DPP rows. 4 edges/iter: clamp-free main
// loop to mindeg, clamped+masked tail to maxdeg. xl gathered as BF16x4
// (uint2, 8B/lane = 256B/row) and unpacked with shift/mask; acc fp32.
__global__ __launch_bounds__(256) void k_fused1(const unsigned short* __restrict__ xl,
                                                const float* __restrict__ xr,
                                                const int* __restrict__ row_ptr,
                                                const int* __restrict__ csr_src,
                                                const float* __restrict__ att1,
                                                const float* __restrict__ b1,
                                                const float* __restrict__ W2l,
                                                const float* __restrict__ W2r,
                                                float* __restrict__ xl2,
                                                float* __restrict__ xr2, int n) {
  int wid  = (blockIdx.x * 256 + threadIdx.x) >> 6;
  int lane = threadIdx.x & 63;
  int sub  = lane & 31;
  int node = min(wid * 2 + (lane >> 5), n - 1);  // dup of last node is benign
  int ch = sub * 4;
  const char* xlb = (const char*)xl;
  unsigned chb = (unsigned)sub * 8u;  // byte offset within 256B bf16 row
  float4 xrv = *(const float4*)&xr[(size_t)node * 128 + ch];
  float4 atv = *(const float4*)&att1[ch];
  atv.x *= LOG2E; atv.y *= LOG2E; atv.z *= LOG2E; atv.w *= LOG2E;
  int s0 = row_ptr[node];
  int deg = row_ptr[node + 1] - s0;  // >=1 (self-loop)
  int odeg = __shfl_xor(deg, 32);
  int mindeg = min(deg, odeg);  // wave-uniform
  int maxdeg = max(deg, odeg);  // wave-uniform
  const int* sp = csr_src + s0;

  float m = -1e30f, l = 0.f;
  float4 acc = make_float4(0.f, 0.f, 0.f, 0.f);

  float t0, t1, t2, t3;
#define UNPACK(dst, q)                                                  \
    dst.x = __uint_as_float(q.x << 16);                                 \
    dst.y = __uint_as_float(q.x & 0xFFFF0000u);                         \
    dst.z = __uint_as_float(q.y << 16);                                 \
    dst.w = __uint_as_float(q.y & 0xFFFF0000u);
#define LOGIT(p, v)                                                     \
    t0 = v.x + xrv.x; t0 = fmaxf(t0, 0.2f * t0);                        \
    t1 = v.y + xrv.y; t1 = fmaxf(t1, 0.2f * t1);                        \
    t2 = v.z + xrv.z; t2 = fmaxf(t2, 0.2f * t2);                        \
    t3 = v.w + xrv.w; t3 = fmaxf(t3, 0.2f * t3);                        \
    p = fmaf(t3, atv.w, fmaf(t2, atv.z, fmaf(t1, atv.y, t0 * atv.x)));

#define BODY(CLAMPED)                                                   \
  {                                                                     \
    int sA, sB, sC, sD;                                                 \
    if (CLAMPED) {                                                      \
      int dm1 = deg - 1;                                                \
      sA = sp[min(e + 0, dm1)];                                         \
      sB = sp[min(e + 1, dm1)];                                         \
      sC = sp[min(e + 2, dm1)];                                         \
      sD = sp[min(e + 3, dm1)];                                         \
    } else {                                                            \
      sA = sp[e + 0]; sB = sp[e + 1]; sC = sp[e + 2]; sD = sp[e + 3];   \
    }                                                                   \
    uint2 qa = *(const uint2*)(xlb + (((unsigned)sA << 8) + chb));      \
    uint2 qb = *(const uint2*)(xlb + (((unsigned)sB << 8) + chb));      \
    uint2 qc = *(const uint2*)(xlb + (((unsigned)sC << 8) + chb));      \
    uint2 qd = *(const uint2*)(xlb + (((unsigned)sD << 8) + chb));      \
    float4 xa, xb, xc, xd;                                              \
    UNPACK(xa, qa) UNPACK(xb, qb) UNPACK(xc, qc) UNPACK(xd, qd)         \
    float pa, pb, pc, pd;                                               \
    LOGIT(pa, xa) LOGIT(pb, xb) LOGIT(pc, xc) LOGIT(pd, xd)             \
    pa = rowsum16(pa);                                                  \
    pb = rowsum16(pb);                                                  \
    pc = rowsum16(pc);                                                  \
    pd = rowsum16(pd);                                                  \
    if (CLAMPED) {                                                      \
      pa = (e + 0 < deg) ? pa : -1e30f;                                 \
      pb = (e + 1 < deg) ? pb : -1e30f;                                 \
      pc = (e + 2 < deg) ? pc : -1e30f;                                 \
      pd = (e + 3 < deg) ? pd : -1e30f;                                 \
    }                                                                   \
    float mn = fmaxf(m, fmaxf(fmaxf(pa, pb), fmaxf(pc, pd)));           \
    float sc = exp2f(m - mn);                                           \
    float wa = exp2f(pa - mn);                                          \
    float wb = exp2f(pb - mn);                                          \
    float wc = exp2f(pc - mn);                                          \
    float wd = exp2f(pd - mn);                                          \
    acc.x = fmaf(wd, xd.x, fmaf(wc, xc.x, fmaf(wb, xb.x, fmaf(wa, xa.x, acc.x * sc)))); \
    acc.y = fmaf(wd, xd.y, fmaf(wc, xc.y, fmaf(wb, xb.y, fmaf(wa, xa.y, acc.y * sc)))); \
    acc.z = fmaf(wd, xd.z, fmaf(wc, xc.z, fmaf(wb, xb.z, fmaf(wa, xa.z, acc.z * sc)))); \
    acc.w = fmaf(wd, xd.w, fmaf(wc, xc.w, fmaf(wb, xb.w, fmaf(wa, xa.w, acc.w * sc)))); \
    l = fmaf(l, sc, wa + wb + wc + wd);                                 \
    m = mn;                                                             \
  }

  int e = 0;
  for (; e + 4 <= mindeg; e += 4) BODY(false)
  for (; e < maxdeg; e += 4) BODY(true)
#undef BODY
#undef LOGIT
#undef UNPACK

  float inv = 1.f / (l + 1e-16f);
  float4 b1v = *(const float4*)&b1[ch];
  float4 h;
  h.x = acc.x * inv + b1v.x; h.x = h.x > 0.f ? h.x : expm1f(h.x);
  h.y = acc.y * inv + b1v.y; h.y = h.y > 0.f ? h.y : expm1f(h.y);
  h.z = acc.z * inv + b1v.z; h.z = h.z > 0.f ? h.z : expm1f(h.z);
  h.w = acc.w * inv + b1v.w; h.w = h.w > 0.f ? h.w : expm1f(h.w);

  float4 u0 = *(const float4*)&W2l[ch * 3 + 0];
  float4 u1 = *(const float4*)&W2l[ch * 3 + 4];
  float4 u2 = *(const float4*)&W2l[ch * 3 + 8];
  float al0 = fmaf(h.w, u2.y, fmaf(h.z, u1.z, fmaf(h.y, u0.w, h.x * u0.x)));
  float al1 = fmaf(h.w, u2.z, fmaf(h.z, u1.w, fmaf(h.y, u1.x, h.x * u0.y)));
  float al2 = fmaf(h.w, u2.w, fmaf(h.z, u2.x, fmaf(h.y, u1.y, h.x * u0.z)));
  float4 v0 = *(const float4*)&W2r[ch * 3 + 0];
  float4 v1 = *(const float4*)&W2r[ch * 3 + 4];
  float4 v2 = *(const float4*)&W2r[ch * 3 + 8];
  float ar0 = fmaf(h.w, v2.y, fmaf(h.z, v1.z, fmaf(h.y, v0.w, h.x * v0.x)));
  float ar1 = fmaf(h.w, v2.z, fmaf(h.z, v1.w, fmaf(h.y, v1.x, h.x * v0.y)));
  float ar2 = fmaf(h.w, v2.w, fmaf(h.z, v2.x, fmaf(h.y, v1.y, h.x * v0.z)));
#pragma unroll
  for (int off = 1; off < 32; off <<= 1) {
    al0 += __shfl_xor(al0, off); al1 += __shfl_xor(al1, off);
    al2 += __shfl_xor(al2, off); ar0 += __shfl_xor(ar0, off);
    ar1 += __shfl_xor(ar1, off); ar2 += __shfl_xor(ar2, off);
  }
  if (sub == 0 && wid * 2 + (lane >> 5) < n) {
    *(float4*)&xl2[node * 4] = make_float4(al0, al1, al2, 0.f);
    *(float4*)&xr2[node * 4] = make_float4(ar0, ar1, ar2, 0.f);
  }
}

// ---------------------------------------------------------------------------
// fused layer-2 edge phase + mean-pool. 16 lanes per node (= one DPP row);
// per-lane online softmax (exp2 domain) over a 16-stride slice, DPP rotate
// merge of (m,l,acc3) states. Pool pre-reduced in LDS.
__global__ __launch_bounds__(256) void k_fused2(const float* __restrict__ xl2,
                                                const float* __restrict__ xr2,
                                                const int* __restrict__ row_ptr,
                                                const int* __restrict__ csr_src,
                                                const float* __restrict__ att2,
                                                const float* __restrict__ b2,
                                                const int* __restrict__ batch,
                                                float* __restrict__ gsum,
                                                float* __restrict__ gcnt, int n) {
  __shared__ float ls[NGRAPH * 3];
  __shared__ float lc[NGRAPH];
  int t = threadIdx.x;
  for (int i = t; i < NGRAPH * 3; i += 256) ls[i] = 0.f;
  for (int i = t; i < NGRAPH; i += 256) lc[i] = 0.f;
  __syncthreads();

  int node = (blockIdx.x * 256 + t) >> 4;  // 16 nodes per block
  int lane = t & 15;
  if (node < n) {
    float4 xrv = *(const float4*)&xr2[node * 4];
    float c0 = att2[0] * LOG2E, c1 = att2[1] * LOG2E, c2 = att2[2] * LOG2E;
    int s0 = row_ptr[node], s1 = row_ptr[node + 1];
    float m = -1e30f, l = 0.f, a0 = 0.f, a1 = 0.f, a2 = 0.f;
    for (int slot = s0 + lane; slot < s1; slot += 16) {
      int s = csr_src[slot];
      float4 xlv = *(const float4*)&xl2[s * 4];
      float t0 = xlv.x + xrv.x; t0 = fmaxf(t0, 0.2f * t0);
      float t1 = xlv.y + xrv.y; t1 = fmaxf(t1, 0.2f * t1);
      float t2 = xlv.z + xrv.z; t2 = fmaxf(t2, 0.2f * t2);
      float p = fmaf(t2, c2, fmaf(t1, c1, t0 * c0));
      float mn = fmaxf(m, p);
      float sc = exp2f(m - mn);
      float w  = exp2f(p - mn);
      a0 = a0 * sc + w * xlv.x;
      a1 = a1 * sc + w * xlv.y;
      a2 = a2 * sc + w * xlv.z;
      l = l * sc + w;
      m = mn;
    }
#define MERGE(C)                                                        \
    {                                                                   \
      float m2 = DPP_ROR(C, m);                                         \
      float l2 = DPP_ROR(C, l);                                         \
      float b0 = DPP_ROR(C, a0);                                        \
      float b1v = DPP_ROR(C, a1);                                       \
      float b2v = DPP_ROR(C, a2);                                       \
      float mn = fmaxf(m, m2);                                          \
      float sA = exp2f(m - mn);                                         \
      float sB = exp2f(m2 - mn);                                        \
      a0 = a0 * sA + b0 * sB;                                           \
      a1 = a1 * sA + b1v * sB;                                          \
      a2 = a2 * sA + b2v * sB;                                          \
      l = l * sA + l2 * sB;                                             \
      m = mn;                                                           \
    }
    MERGE(8) MERGE(4) MERGE(2) MERGE(1)
#undef MERGE
    if (lane == 0) {
      float inv = 1.f / (l + 1e-16f);
      float o0 = a0 * inv + b2[0];
      float o1 = a1 * inv + b2[1];
      float o2 = a2 * inv + b2[2];
      int b = batch[node];
      atomicAdd(&ls[b * 3 + 0], o0);
      atomicAdd(&ls[b * 3 + 1], o1);
      atomicAdd(&ls[b * 3 + 2], o2);
      atomicAdd(&lc[b], 1.f);
    }
  }
  __syncthreads();
  for (int i = t; i < NGRAPH * 3; i += 256)
    if (ls[i] != 0.f) atomicAdd(&gsum[i], ls[i]);
  for (int i = t; i < NGRAPH; i += 256)
    if (lc[i] != 0.f) atomicAdd(&gcnt[i], lc[i]);
}

// 1 block, 64 threads: per-graph mean + 2-layer MLP
__global__ __launch_bounds__(64) void k_mlp(const float* __restrict__ gsum,
                                            const float* __restrict__ gcnt,
                                            const float* __restrict__ Wr1,
                                            const float* __restrict__ br1,
                                            const float* __restrict__ Wr2,
                                            const float* __restrict__ br2,
                                            float* __restrict__ out) {
  int t = threadIdx.x;
  if (t >= NGRAPH) return;
  float cnt = fmaxf(gcnt[t], 1.f);
  float g0 = gsum[t * 3 + 0] / cnt;
  float g1 = gsum[t * 3 + 1] / cnt;
  float g2 = gsum[t * 3 + 2] / cnt;
  float o0 = br2[0], o1 = br2[1], o2 = br2[2];
  for (int j = 0; j < 64; ++j) {
    float hj = g0 * Wr1[j] + g1 * Wr1[64 + j] + g2 * Wr1[128 + j] + br1[j];
    hj = fmaxf(hj, 0.f);
    o0 = fmaf(hj, Wr2[j * 3 + 0], o0);
    o1 = fmaf(hj, Wr2[j * 3 + 1], o1);
    o2 = fmaf(hj, Wr2[j * 3 + 2], o2);
  }
  out[t * 3 + 0] = o0;
  out[t * 3 + 1] = o1;
  out[t * 3 + 2] = o2;
}

// ---------------------------------------------------------------------------
extern "C" void kernel_launch(void* const* d_in, const int* in_sizes, int n_in,
                              void* d_out, int out_size, void* d_ws, size_t ws_size,
                              hipStream_t stream) {
  const float* x    = (const float*)d_in[0];
  const int*   ei   = (const int*)d_in[1];
  const int*   batch= (const int*)d_in[2];
  const float* W1l  = (const float*)d_in[3];
  const float* W1r  = (const float*)d_in[4];
  const float* att1 = (const float*)d_in[5];
  const float* b1   = (const float*)d_in[6];
  const float* W2l  = (const float*)d_in[7];
  const float* W2r  = (const float*)d_in[8];
  const float* att2 = (const float*)d_in[9];
  const float* b2   = (const float*)d_in[10];
  const float* Wr1  = (const float*)d_in[11];
  const float* br1  = (const float*)d_in[12];
  const float* Wr2  = (const float*)d_in[13];
  const float* br2  = (const float*)d_in[14];
  float* out = (float*)d_out;

  const int N  = in_sizes[0] / 128;
  const int E  = in_sizes[1] / 2;
  const int Et = E + N;
  const int NB = (N + 1023) / 1024;  // scan blocks (<=64)

  char* p = (char*)d_ws;
  auto alloc = [&](size_t bytes) -> char* {
    char* r = p;
    p += (bytes + 255) & ~(size_t)255;
    return r;
  };
  unsigned short* xl1 = (unsigned short*)alloc((size_t)N * 128 * 2);  // bf16
  float*    xr1    = (float*)alloc((size_t)N * 128 * 4);
  int*      row_ptr= (int*)alloc((size_t)(N + 1) * 4);
  int*      csr_src= (int*)alloc((size_t)Et * 4);
  int*      rank   = (int*)alloc((size_t)Et * 4);
  int*      bsum   = (int*)alloc(64 * 4);
  // zero-init group (one memset): deg | gsum | gcnt
  char*     z0     = p;
  int*      deg    = (int*)alloc((size_t)N * 4);
  float*    gsum   = (float*)alloc(NGRAPH * 3 * 4);
  float*    gcnt   = (float*)alloc(NGRAPH * 4);
  size_t    zbytes = (size_t)(p - z0);
  float*    xl2    = (float*)alloc((size_t)N * 4 * 4);
  float*    xr2    = (float*)alloc((size_t)N * 4 * 4);

  hipMemsetAsync(z0, 0, zbytes, stream);
  hipLaunchKernelGGL(k_deg, dim3((Et + 255) / 256), dim3(256), 0, stream,
                     ei, E, Et, deg, rank);
  hipLaunchKernelGGL(k_scan_part, dim3(NB), dim3(256), 0, stream, deg, bsum, N);
  hipLaunchKernelGGL(k_scan_top, dim3(1), dim3(64), 0, stream, bsum, NB);
  hipLaunchKernelGGL(k_scan_write, dim3(NB), dim3(256), 0, stream,
                     deg, bsum, row_ptr, N);
  hipLaunchKernelGGL(k_fill, dim3((Et + 255) / 256), dim3(256), 0, stream,
                     ei, E, Et, row_ptr, rank, csr_src);
  hipLaunchKernelGGL(k_gemm128, dim3((N + 63) / 64), dim3(128), 0, stream,
                     x, W1l, W1r, xl1, xr1, N);
  int waves1 = (N + 1) / 2;
  hipLaunchKernelGGL(k_fused1, dim3((waves1 * 64 + 255) / 256), dim3(256), 0, stream,
                     xl1, xr1, row_ptr, csr_src, att1, b1, W2l, W2r, xl2, xr2, N);
  hipLaunchKernelGGL(k_fused2, dim3((N * 16 + 255) / 256), dim3(256), 0, stream,
                     xl2, xr2, row_ptr, csr_src, att2, b2, batch, gsum, gcnt, N);
  hipLaunchKernelGGL(k_mlp, dim3(1), dim3(64), 0, stream,
                     gsum, gcnt, Wr1, br1, Wr2, br2, out);
}

// Round 15
// 319.955 us; speedup vs baseline: 1.0479x; 1.0479x over previous
//
#include <hip/hip_runtime.h>

// ---------------------------------------------------------------------------
// GATv2 (2 layers) + mean-pool + MLP for MI355X.
// N=50000 nodes, E=800000 edges (+N self loops), IN=128, HID=64, HEADS=2,
// OUT=3, 64 graphs. Output: [64,3] float32.
// R1: k_agg2 pool atomic storm fixed (LDS pre-reduction). 1128 -> 803 us.
// R2: CSR + per-node online softmax; edge phases fused.   803 -> 515 us.
// R3: fused1 2-edge ILP + reg src cache + W2-proj fused.   515 -> 394 us.
// R4: fused1 2 nodes/wave + 4-edge ILP + batched softmax.  394 -> 368 us.
// R5: gemm 128x128 reg-blocked (LDS 72KB->16KB).            368 -> 343 us.
// R6: DPP rotate-reduce + exp2 domain; gemm 64x128/4x8.     343 -> 337 us.
// R7: 8-edge unroll flat. R8-R10: degree-sort detour regressed; reverted.
// R11: 3-phase parallel scan (single-block scan was 100us!). 422 -> 329 us.
// R12: xl1 message table bf16 (gather 512->256B/edge).       329 -> 326 us.
// R13: k_fill atomic-free (rank from k_deg); gemm merged.    326 -> 286 us.
// R14: 8x16 micro-tile REGRESSED 286->335: VGPR 208 + 128-thr blocks ->
//     occupancy 8% (1564 waves on 1024 SIMDs). Lesson (same as R7): acc
//     register cost beats arithmetic-intensity gains. R13 gemm was VALU-
//     issue-efficient (26us busy ~ 21us FMA floor); its 60% idle = latency
//     at 3 blocks/CU.
// R15: occupancy-first gemm: 32-row x 256-col tile, 256 thr, 4x8 micro
//     (acc 32, VGPR ~80), grid 1563 = 6.1 blocks/CU. Per k: 3 b128 reads
//     vs 64 FMA-cyc (LDS hidden). W strided x12 floats. Bit-identical.
// ---------------------------------------------------------------------------

#define NGRAPH 64
#define LOG2E 1.4426950408889634f

// v_mov_dpp row_ror:k (16-lane rows). Valid reduce permutation for
// commutative ops; leaves every lane of the row with the full result.
#define DPP_ROR(C, x) \
  __int_as_float(__builtin_amdgcn_update_dpp(0, __float_as_int(x), (0x120 | C), 0xF, 0xF, false))

__device__ __forceinline__ float rowsum16(float v) {
  v += DPP_ROR(8, v);
  v += DPP_ROR(4, v);
  v += DPP_ROR(2, v);
  v += DPP_ROR(1, v);
  return v;
}

__device__ __forceinline__ unsigned bf16rne(float f) {
  unsigned u = __float_as_uint(f);
  return (u + 0x7FFFu + ((u >> 16) & 1u)) >> 16;
}

// ---------------------------------------------------------------------------
// The atomic's return value IS this edge's rank among its dst's edges.
__global__ void k_deg(const int* __restrict__ ei, int E, int Et,
                      int* __restrict__ deg, int* __restrict__ rank) {
  int e = blockIdx.x * blockDim.x + threadIdx.x;
  if (e >= Et) return;
  int d = (e < E) ? ei[E + e] : (e - E);  // dst only
  rank[e] = atomicAdd(&deg[d], 1);        // coalesced store of the rank
}

// ---------------------------------------------------------------------------
// 3-phase parallel exclusive scan of deg[0..n) -> row_ptr[0..n].
__global__ __launch_bounds__(256) void k_scan_part(const int* __restrict__ deg,
                                                   int* __restrict__ bsum, int n) {
  __shared__ int sd[256];
  int t = threadIdx.x;
  int i = blockIdx.x * 1024 + t * 4;
  int s = 0;
  if (i + 4 <= n) {
    int4 d = *(const int4*)&deg[i];
    s = d.x + d.y + d.z + d.w;
  } else {
    for (int j = i; j < min(i + 4, n); ++j) s += deg[j];
  }
  sd[t] = s;
  __syncthreads();
  for (int off = 128; off; off >>= 1) {
    if (t < off) sd[t] += sd[t + off];
    __syncthreads();
  }
  if (t == 0) bsum[blockIdx.x] = sd[0];
}

__global__ __launch_bounds__(64) void k_scan_top(int* __restrict__ bsum, int nb) {
  __shared__ int s[64];
  int t = threadIdx.x;
  s[t] = (t < nb) ? bsum[t] : 0;
  __syncthreads();
  int acc = 0;
  for (int j = 0; j < t; ++j) acc += s[j];
  if (t < nb) bsum[t] = acc;
}

__global__ __launch_bounds__(256) void k_scan_write(const int* __restrict__ deg,
                                                    const int* __restrict__ bsum,
                                                    int* __restrict__ row_ptr, int n) {
  __shared__ int sd[256];
  int t = threadIdx.x;
  int i = blockIdx.x * 1024 + t * 4;
  int4 d = make_int4(0, 0, 0, 0);
  bool full = (i + 4 <= n);
  if (full) d = *(const int4*)&deg[i];
  else {
    if (i + 0 < n) d.x = deg[i + 0];
    if (i + 1 < n) d.y = deg[i + 1];
    if (i + 2 < n) d.z = deg[i + 2];
    if (i + 3 < n) d.w = deg[i + 3];
  }
  int s = d.x + d.y + d.z + d.w;
  sd[t] = s;
  __syncthreads();
  for (int off = 1; off < 256; off <<= 1) {  // Hillis-Steele inclusive
    int v = (t >= off) ? sd[t - off] : 0;
    __syncthreads();
    sd[t] += v;
    __syncthreads();
  }
  int ex = sd[t] - s + bsum[blockIdx.x];
  int4 r;
  r.x = ex;
  r.y = ex + d.x;
  r.z = r.y + d.y;
  r.w = r.z + d.z;
  if (full) {
    *(int4*)&row_ptr[i] = r;
    if (i + 4 == n) row_ptr[n] = r.w + d.w;
  } else if (i < n) {
    int run = ex;
    int vals[4] = {d.x, d.y, d.z, d.w};
    for (int j = 0; j < 4 && i + j < n; ++j) {
      row_ptr[i + j] = run;
      run += vals[j];
    }
    if (i <= n && i + 4 > n) row_ptr[n] = run;
  }
}

// no atomic — slot is row_ptr[d] + precomputed rank.
__global__ void k_fill(const int* __restrict__ ei, int E, int Et,
                       const int* __restrict__ row_ptr,
                       const int* __restrict__ rank,
                       int* __restrict__ csr_src) {
  int e = blockIdx.x * blockDim.x + threadIdx.x;
  if (e >= Et) return;
  int s, d;
  if (e < E) { s = ei[e]; d = ei[E + e]; }
  else       { s = e - E; d = s; }
  csr_src[row_ptr[d] + rank[e]] = s;
}

// ---------------------------------------------------------------------------
// R15: one dispatch computes xl1 = x@W1l (BF16 out) AND xr1 = x@W1r (fp32).
// Block: 32 rows x 256 combined cols, 256 threads, 4x8 micro-tile (acc=32).
// rg = t>>5 (rows rg*4..+3), cg = t&31 (combined cols cg*8..+7).
// Per k: 1 a-b128 + 2 b-b128 (48 B) feeding 64 FMA-cycles -> LDS hidden.
// W col-groups stored at stride 12 floats (16B-aligned, <=4-way banks).
// Grid 1563 blocks = 6.1/CU. FMA k-order per output element identical to
// R12/R13 (bit-identical results).
__global__ __launch_bounds__(256) void k_gemm128(const float* __restrict__ x,
                                                 const float* __restrict__ Wl,
                                                 const float* __restrict__ Wr,
                                                 unsigned short* __restrict__ outl,
                                                 float* __restrict__ outr, int n) {
  __shared__ __align__(16) float xs[16][40];    // x tile transposed [k][row]
  __shared__ __align__(16) float wsc[16][384];  // combined W: [k][cg*12 + j]
  int t = threadIdx.x;
  int rg = t >> 5;   // 0..7  -> rows rg*4..+3
  int cg = t & 31;   // 0..31 -> combined cols cg*8..+7
  int r0 = blockIdx.x * 32;
  float acc[4][8] = {};

  int sr = t & 31;          // x staging row (t<128)
  int skq = (t >> 5) & 3;   // x staging k-quad

  for (int k0 = 0; k0 < 128; k0 += 16) {
    float4 xv = make_float4(0.f, 0.f, 0.f, 0.f);
    if (t < 128) {
      int gr = r0 + sr;
      if (gr < n) xv = *(const float4*)&x[(size_t)gr * 128 + k0 + skq * 4];
    }
    float4 wv[4];
#pragma unroll
    for (int p = 0; p < 4; ++p) {
      int idx = t + 256 * p;
      int k = idx >> 6, cq = idx & 63;
      const float* src = (cq < 32) ? &Wl[(size_t)(k0 + k) * 128 + cq * 4]
                                   : &Wr[(size_t)(k0 + k) * 128 + (cq - 32) * 4];
      wv[p] = *(const float4*)src;
    }
    __syncthreads();
    if (t < 128) {
      xs[skq * 4 + 0][sr] = xv.x;
      xs[skq * 4 + 1][sr] = xv.y;
      xs[skq * 4 + 2][sr] = xv.z;
      xs[skq * 4 + 3][sr] = xv.w;
    }
#pragma unroll
    for (int p = 0; p < 4; ++p) {
      int idx = t + 256 * p;
      int k = idx >> 6, cq = idx & 63;
      *(float4*)&wsc[k][(cq >> 1) * 12 + (cq & 1) * 4] = wv[p];
    }
    __syncthreads();
#pragma unroll
    for (int k = 0; k < 16; ++k) {
      float4 av = *(const float4*)&xs[k][rg * 4];
      float4 b0 = *(const float4*)&wsc[k][cg * 12 + 0];
      float4 b1 = *(const float4*)&wsc[k][cg * 12 + 4];
      float a[4] = {av.x, av.y, av.z, av.w};
      float b[8] = {b0.x, b0.y, b0.z, b0.w, b1.x, b1.y, b1.z, b1.w};
#pragma unroll
      for (int i = 0; i < 4; ++i)
#pragma unroll
        for (int j = 0; j < 8; ++j)
          acc[i][j] = fmaf(a[i], b[j], acc[i][j]);
    }
  }
  if (cg < 16) {  // bf16 xl1 columns cg*8..+7
#pragma unroll
    for (int i = 0; i < 4; ++i) {
      int gr = r0 + rg * 4 + i;
      if (gr < n) {
        uint4 q;
        q.x = bf16rne(acc[i][0]) | (bf16rne(acc[i][1]) << 16);
        q.y = bf16rne(acc[i][2]) | (bf16rne(acc[i][3]) << 16);
        q.z = bf16rne(acc[i][4]) | (bf16rne(acc[i][5]) << 16);
        q.w = bf16rne(acc[i][6]) | (bf16rne(acc[i][7]) << 16);
        *(uint4*)&outl[(size_t)gr * 128 + cg * 8] = q;
      }
    }
  } else {  // fp32 xr1 columns (cg-16)*8..+7
    int c0 = (cg - 16) * 8;
#pragma unroll
    for (int i = 0; i < 4; ++i) {
      int gr = r0 + rg * 4 + i;
      if (gr < n) {
        *(float4*)&outr[(size_t)gr * 128 + c0 + 0] =
            make_float4(acc[i][0], acc[i][1], acc[i][2], acc[i][3]);
        *(float4*)&outr[(size_t)gr * 128 + c0 + 4] =
            make_float4(acc[i][4], acc[i][5], acc[i][6], acc[i][7]);
      }
    }
  }
}

// ---------------------------------------------------------------------------
// fused layer-1 edge phase + layer-2 input projection.
// TWO nodes per wave: lanes 0-31 = node 2w, 32-63 = node 2w+1. Lane holds 4
// channels; 16-lane head groups = DPP rows. 4 edges/iter: clamp-free main
// loop to mindeg, clamped+masked tail to maxdeg. xl gathered as BF16x4
// (uint2, 8B/lane = 256B/row) and unpacked with shift/mask; acc fp32.
__global__ __launch_bounds__(256) void k_fused1(const unsigned short* __restrict__ xl,
                                                const float* __restrict__ xr,
                                                const int* __restrict__ row_ptr,
                                                const int* __restrict__ csr_src,
                                                const float* __restrict__ att1,
                                                const float* __restrict__ b1,
                                                const float* __restrict__ W2l,
                                                const float* __restrict__ W2r,
                                                float* __restrict__ xl2,
                                                float* __restrict__ xr2, int n) {
  int wid  = (blockIdx.x * 256 + threadIdx.x) >> 6;
  int lane = threadIdx.x & 63;
  int sub  = lane & 31;
  int node = min(wid * 2 + (lane >> 5), n - 1);  // dup of last node is benign
  int ch = sub * 4;
  const char* xlb = (const char*)xl;
  unsigned chb = (unsigned)sub * 8u;  // byte offset within 256B bf16 row
  float4 xrv = *(const float4*)&xr[(size_t)node * 128 + ch];
  float4 atv = *(const float4*)&att1[ch];
  atv.x *= LOG2E; atv.y *= LOG2E; atv.z *= LOG2E; atv.w *= LOG2E;
  int s0 = row_ptr[node];
  int deg = row_ptr[node + 1] - s0;  // >=1 (self-loop)
  int odeg = __shfl_xor(deg, 32);
  int mindeg = min(deg, odeg);  // wave-uniform
  int maxdeg = max(deg, odeg);  // wave-uniform
  const int* sp = csr_src + s0;

  float m = -1e30f, l = 0.f;
  float4 acc = make_float4(0.f, 0.f, 0.f, 0.f);

  float t0, t1, t2, t3;
#define UNPACK(dst, q)                                                  \
    dst.x = __uint_as_float(q.x << 16);                                 \
    dst.y = __uint_as_float(q.x & 0xFFFF0000u);                         \
    dst.z = __uint_as_float(q.y << 16);                                 \
    dst.w = __uint_as_float(q.y & 0xFFFF0000u);
#define LOGIT(p, v)                                                     \
    t0 = v.x + xrv.x; t0 = fmaxf(t0, 0.2f * t0);                        \
    t1 = v.y + xrv.y; t1 = fmaxf(t1, 0.2f * t1);                        \
    t2 = v.z + xrv.z; t2 = fmaxf(t2, 0.2f * t2);                        \
    t3 = v.w + xrv.w; t3 = fmaxf(t3, 0.2f * t3);                        \
    p = fmaf(t3, atv.w, fmaf(t2, atv.z, fmaf(t1, atv.y, t0 * atv.x)));

#define BODY(CLAMPED)                                                   \
  {                                                                     \
    int sA, sB, sC, sD;                                                 \
    if (CLAMPED) {                                                      \
      int dm1 = deg - 1;                                                \
      sA = sp[min(e + 0, dm1)];                                         \
      sB = sp[min(e + 1, dm1)];                                         \
      sC = sp[min(e + 2, dm1)];                                         \
      sD = sp[min(e + 3, dm1)];                                         \
    } else {                                                            \
      sA = sp[e + 0]; sB = sp[e + 1]; sC = sp[e + 2]; sD = sp[e + 3];   \
    }                                                                   \
    uint2 qa = *(const uint2*)(xlb + (((unsigned)sA << 8) + chb));      \
    uint2 qb = *(const uint2*)(xlb + (((unsigned)sB << 8) + chb));      \
    uint2 qc = *(const uint2*)(xlb + (((unsigned)sC << 8) + chb));      \
    uint2 qd = *(const uint2*)(xlb + (((unsigned)sD << 8) + chb));      \
    float4 xa, xb, xc, xd;                                              \
    UNPACK(xa, qa) UNPACK(xb, qb) UNPACK(xc, qc) UNPACK(xd, qd)         \
    float pa, pb, pc, pd;                                               \
    LOGIT(pa, xa) LOGIT(pb, xb) LOGIT(pc, xc) LOGIT(pd, xd)             \
    pa = rowsum16(pa);                                                  \
    pb = rowsum16(pb);                                                  \
    pc = rowsum16(pc);                                                  \
    pd = rowsum16(pd);                                                  \
    if (CLAMPED) {                                                      \
      pa = (e + 0 < deg) ? pa : -1e30f;                                 \
      pb = (e + 1 < deg) ? pb : -1e30f;                                 \
      pc = (e + 2 < deg) ? pc : -1e30f;                                 \
      pd = (e + 3 < deg) ? pd : -1e30f;                                 \
    }                                                                   \
    float mn = fmaxf(m, fmaxf(fmaxf(pa, pb), fmaxf(pc, pd)));           \
    float sc = exp2f(m - mn);                                           \
    float wa = exp2f(pa - mn);                                          \
    float wb = exp2f(pb - mn);                                          \
    float wc = exp2f(pc - mn);                                          \
    float wd = exp2f(pd - mn);                                          \
    acc.x = fmaf(wd, xd.x, fmaf(wc, xc.x, fmaf(wb, xb.x, fmaf(wa, xa.x, acc.x * sc)))); \
    acc.y = fmaf(wd, xd.y, fmaf(wc, xc.y, fmaf(wb, xb.y, fmaf(wa, xa.y, acc.y * sc)))); \
    acc.z = fmaf(wd, xd.z, fmaf(wc, xc.z, fmaf(wb, xb.z, fmaf(wa, xa.z, acc.z * sc)))); \
    acc.w = fmaf(wd, xd.w, fmaf(wc, xc.w, fmaf(wb, xb.w, fmaf(wa, xa.w, acc.w * sc)))); \
    l = fmaf(l, sc, wa + wb + wc + wd);                                 \
    m = mn;                                                             \
  }

  int e = 0;
  for (; e + 4 <= mindeg; e += 4) BODY(false)
  for (; e < maxdeg; e += 4) BODY(true)
#undef BODY
#undef LOGIT
#undef UNPACK

  float inv = 1.f / (l + 1e-16f);
  float4 b1v = *(const float4*)&b1[ch];
  float4 h;
  h.x = acc.x * inv + b1v.x; h.x = h.x > 0.f ? h.x : expm1f(h.x);
  h.y = acc.y * inv + b1v.y; h.y = h.y > 0.f ? h.y : expm1f(h.y);
  h.z = acc.z * inv + b1v.z; h.z = h.z > 0.f ? h.z : expm1f(h.z);
  h.w = acc.w * inv + b1v.w; h.w = h.w > 0.f ? h.w : expm1f(h.w);

  float4 u0 = *(const float4*)&W2l[ch * 3 + 0];
  float4 u1 = *(const float4*)&W2l[ch * 3 + 4];
  float4 u2 = *(const float4*)&W2l[ch * 3 + 8];
  float al0 = fmaf(h.w, u2.y, fmaf(h.z, u1.z, fmaf(h.y, u0.w, h.x * u0.x)));
  float al1 = fmaf(h.w, u2.z, fmaf(h.z, u1.w, fmaf(h.y, u1.x, h.x * u0.y)));
  float al2 = fmaf(h.w, u2.w, fmaf(h.z, u2.x, fmaf(h.y, u1.y, h.x * u0.z)));
  float4 v0 = *(const float4*)&W2r[ch * 3 + 0];
  float4 v1 = *(const float4*)&W2r[ch * 3 + 4];
  float4 v2 = *(const float4*)&W2r[ch * 3 + 8];
  float ar0 = fmaf(h.w, v2.y, fmaf(h.z, v1.z, fmaf(h.y, v0.w, h.x * v0.x)));
  float ar1 = fmaf(h.w, v2.z, fmaf(h.z, v1.w, fmaf(h.y, v1.x, h.x * v0.y)));
  float ar2 = fmaf(h.w, v2.w, fmaf(h.z, v2.x, fmaf(h.y, v1.y, h.x * v0.z)));
#pragma unroll
  for (int off = 1; off < 32; off <<= 1) {
    al0 += __shfl_xor(al0, off); al1 += __shfl_xor(al1, off);
    al2 += __shfl_xor(al2, off); ar0 += __shfl_xor(ar0, off);
    ar1 += __shfl_xor(ar1, off); ar2 += __shfl_xor(ar2, off);
  }
  if (sub == 0 && wid * 2 + (lane >> 5) < n) {
    *(float4*)&xl2[node * 4] = make_float4(al0, al1, al2, 0.f);
    *(float4*)&xr2[node * 4] = make_float4(ar0, ar1, ar2, 0.f);
  }
}

// ---------------------------------------------------------------------------
// fused layer-2 edge phase + mean-pool. 16 lanes per node (= one DPP row);
// per-lane online softmax (exp2 domain) over a 16-stride slice, DPP rotate
// merge of (m,l,acc3) states. Pool pre-reduced in LDS.
__global__ __launch_bounds__(256) void k_fused2(const float* __restrict__ xl2,
                                                const float* __restrict__ xr2,
                                                const int* __restrict__ row_ptr,
                                                const int* __restrict__ csr_src,
                                                const float* __restrict__ att2,
                                                const float* __restrict__ b2,
                                                const int* __restrict__ batch,
                                                float* __restrict__ gsum,
                                                float* __restrict__ gcnt, int n) {
  __shared__ float ls[NGRAPH * 3];
  __shared__ float lc[NGRAPH];
  int t = threadIdx.x;
  for (int i = t; i < NGRAPH * 3; i += 256) ls[i] = 0.f;
  for (int i = t; i < NGRAPH; i += 256) lc[i] = 0.f;
  __syncthreads();

  int node = (blockIdx.x * 256 + t) >> 4;  // 16 nodes per block
  int lane = t & 15;
  if (node < n) {
    float4 xrv = *(const float4*)&xr2[node * 4];
    float c0 = att2[0] * LOG2E, c1 = att2[1] * LOG2E, c2 = att2[2] * LOG2E;
    int s0 = row_ptr[node], s1 = row_ptr[node + 1];
    float m = -1e30f, l = 0.f, a0 = 0.f, a1 = 0.f, a2 = 0.f;
    for (int slot = s0 + lane; slot < s1; slot += 16) {
      int s = csr_src[slot];
      float4 xlv = *(const float4*)&xl2[s * 4];
      float t0 = xlv.x + xrv.x; t0 = fmaxf(t0, 0.2f * t0);
      float t1 = xlv.y + xrv.y; t1 = fmaxf(t1, 0.2f * t1);
      float t2 = xlv.z + xrv.z; t2 = fmaxf(t2, 0.2f * t2);
      float p = fmaf(t2, c2, fmaf(t1, c1, t0 * c0));
      float mn = fmaxf(m, p);
      float sc = exp2f(m - mn);
      float w  = exp2f(p - mn);
      a0 = a0 * sc + w * xlv.x;
      a1 = a1 * sc + w * xlv.y;
      a2 = a2 * sc + w * xlv.z;
      l = l * sc + w;
      m = mn;
    }
#define MERGE(C)                                                        \
    {                                                                   \
      float m2 = DPP_ROR(C, m);                                         \
      float l2 = DPP_ROR(C, l);                                         \
      float b0 = DPP_ROR(C, a0);                                        \
      float b1v = DPP_ROR(C, a1);                                       \
      float b2v = DPP_ROR(C, a2);                                       \
      float mn = fmaxf(m, m2);                                          \
      float sA = exp2f(m - mn);                                         \
      float sB = exp2f(m2 - mn);                                        \
      a0 = a0 * sA + b0 * sB;                                           \
      a1 = a1 * sA + b1v * sB;                                          \
      a2 = a2 * sA + b2v * sB;                                          \
      l = l * sA + l2 * sB;                                             \
      m = mn;                                                           \
    }
    MERGE(8) MERGE(4) MERGE(2) MERGE(1)
#undef MERGE
    if (lane == 0) {
      float inv = 1.f / (l + 1e-16f);
      float o0 = a0 * inv + b2[0];
      float o1 = a1 * inv + b2[1];
      float o2 = a2 * inv + b2[2];
      int b = batch[node];
      atomicAdd(&ls[b * 3 + 0], o0);
      atomicAdd(&ls[b * 3 + 1], o1);
      atomicAdd(&ls[b * 3 + 2], o2);
      atomicAdd(&lc[b], 1.f);
    }
  }
  __syncthreads();
  for (int i = t; i < NGRAPH * 3; i += 256)
    if (ls[i] != 0.f) atomicAdd(&gsum[i], ls[i]);
  for (int i = t; i < NGRAPH; i += 256)
    if (lc[i] != 0.f) atomicAdd(&gcnt[i], lc[i]);
}

// 1 block, 64 threads: per-graph mean + 2-layer MLP
__global__ __launch_bounds__(64) void k_mlp(const float* __restrict__ gsum,
                                            const float* __restrict__ gcnt,
                                            const float* __restrict__ Wr1,
                                            const float* __restrict__ br1,
                                            const float* __restrict__ Wr2,
                                            const float* __restrict__ br2,
                                            float* __restrict__ out) {
  int t = threadIdx.x;
  if (t >= NGRAPH) return;
  float cnt = fmaxf(gcnt[t], 1.f);
  float g0 = gsum[t * 3 + 0] / cnt;
  float g1 = gsum[t * 3 + 1] / cnt;
  float g2 = gsum[t * 3 + 2] / cnt;
  float o0 = br2[0], o1 = br2[1], o2 = br2[2];
  for (int j = 0; j < 64; ++j) {
    float hj = g0 * Wr1[j] + g1 * Wr1[64 + j] + g2 * Wr1[128 + j] + br1[j];
    hj = fmaxf(hj, 0.f);
    o0 = fmaf(hj, Wr2[j * 3 + 0], o0);
    o1 = fmaf(hj, Wr2[j * 3 + 1], o1);
    o2 = fmaf(hj, Wr2[j * 3 + 2], o2);
  }
  out[t * 3 + 0] = o0;
  out[t * 3 + 1] = o1;
  out[t * 3 + 2] = o2;
}

// ---------------------------------------------------------------------------
extern "C" void kernel_launch(void* const* d_in, const int* in_sizes, int n_in,
                              void* d_out, int out_size, void* d_ws, size_t ws_size,
                              hipStream_t stream) {
  const float* x    = (const float*)d_in[0];
  const int*   ei   = (const int*)d_in[1];
  const int*   batch= (const int*)d_in[2];
  const float* W1l  = (const float*)d_in[3];
  const float* W1r  = (const float*)d_in[4];
  const float* att1 = (const float*)d_in[5];
  const float* b1   = (const float*)d_in[6];
  const float* W2l  = (const float*)d_in[7];
  const float* W2r  = (const float*)d_in[8];
  const float* att2 = (const float*)d_in[9];
  const float* b2   = (const float*)d_in[10];
  const float* Wr1  = (const float*)d_in[11];
  const float* br1  = (const float*)d_in[12];
  const float* Wr2  = (const float*)d_in[13];
  const float* br2  = (const float*)d_in[14];
  float* out = (float*)d_out;

  const int N  = in_sizes[0] / 128;
  const int E  = in_sizes[1] / 2;
  const int Et = E + N;
  const int NB = (N + 1023) / 1024;  // scan blocks (<=64)

  char* p = (char*)d_ws;
  auto alloc = [&](size_t bytes) -> char* {
    char* r = p;
    p += (bytes + 255) & ~(size_t)255;
    return r;
  };
  unsigned short* xl1 = (unsigned short*)alloc((size_t)N * 128 * 2);  // bf16
  float*    xr1    = (float*)alloc((size_t)N * 128 * 4);
  int*      row_ptr= (int*)alloc((size_t)(N + 1) * 4);
  int*      csr_src= (int*)alloc((size_t)Et * 4);
  int*      rank   = (int*)alloc((size_t)Et * 4);
  int*      bsum   = (int*)alloc(64 * 4);
  // zero-init group (one memset): deg | gsum | gcnt
  char*     z0     = p;
  int*      deg    = (int*)alloc((size_t)N * 4);
  float*    gsum   = (float*)alloc(NGRAPH * 3 * 4);
  float*    gcnt   = (float*)alloc(NGRAPH * 4);
  size_t    zbytes = (size_t)(p - z0);
  float*    xl2    = (float*)alloc((size_t)N * 4 * 4);
  float*    xr2    = (float*)alloc((size_t)N * 4 * 4);

  hipMemsetAsync(z0, 0, zbytes, stream);
  hipLaunchKernelGGL(k_deg, dim3((Et + 255) / 256), dim3(256), 0, stream,
                     ei, E, Et, deg, rank);
  hipLaunchKernelGGL(k_scan_part, dim3(NB), dim3(256), 0, stream, deg, bsum, N);
  hipLaunchKernelGGL(k_scan_top, dim3(1), dim3(64), 0, stream, bsum, NB);
  hipLaunchKernelGGL(k_scan_write, dim3(NB), dim3(256), 0, stream,
                     deg, bsum, row_ptr, N);
  hipLaunchKernelGGL(k_fill, dim3((Et + 255) / 256), dim3(256), 0, stream,
                     ei, E, Et, row_ptr, rank, csr_src);
  hipLaunchKernelGGL(k_gemm128, dim3((N + 31) / 32), dim3(256), 0, stream,
                     x, W1l, W1r, xl1, xr1, N);
  int waves1 = (N + 1) / 2;
  hipLaunchKernelGGL(k_fused1, dim3((waves1 * 64 + 255) / 256), dim3(256), 0, stream,
                     xl1, xr1, row_ptr, csr_src, att1, b1, W2l, W2r, xl2, xr2, N);
  hipLaunchKernelGGL(k_fused2, dim3((N * 16 + 255) / 256), dim3(256), 0, stream,
                     xl2, xr2, row_ptr, csr_src, att2, b2, batch, gsum, gcnt, N);
  hipLaunchKernelGGL(k_mlp, dim3(1), dim3(64), 0, stream,
                     gsum, gcnt, Wr1, br1, Wr2, br2, out);
}